// Round 4
// baseline (222.615 us; speedup 1.0000x reference)
//
#include <hip/hip_runtime.h>

#define T_STEPS 512
#define PF_D 8            // prefetch distance (timesteps) — ~2000 cyc of cover
#define LOG2E 1.4426950408889634f

typedef float v2f __attribute__((ext_vector_type(2)));

// sigmoid via hw exp2 + rcp; tanh(x) = 2*sigmoid(2x) - 1 (per-lane consts)
__device__ __forceinline__ float fsigmoid(float x) {
    float e = __builtin_amdgcn_exp2f(-LOG2E * x);
    return __builtin_amdgcn_rcpf(1.0f + e);
}

// DPP row rotate-right by R within the 16-lane row (~2-cycle cross-lane, no LDS)
template <int R>
__device__ __forceinline__ float rotf(float v) {
    const int i = __float_as_int(v);
    return __int_as_float(__builtin_amdgcn_update_dpp(i, i, 0x120 | R, 0xF, 0xF, false));
}

// 16 lanes per batch element. Lane l: j = l&7 (hidden unit), p = l>>3.
// p=0 owns gate rows {i:j, f:8+j}; p=1 owns {g:16+j, o:24+j}; pairs packed in
// float2. h all-gathered via DPP row_ror with per-lane-permuted W_hh.
// tanh(x)=2*sigmoid(2x)-1 keeps the activation wave-uniform.
// i*g == actA * rot8(actA) on BOTH halves (select-free); f/o need 2 cndmasks.
// __launch_bounds__(256,2): cap VGPR at 256 so the 8-deep x prefetch actually
// stays in registers (R3's bare launch_bounds gave VGPR=44 -> loads sunk to
// use sites -> ~700cyc/step memory stall).
__global__ __launch_bounds__(256, 2) void lstm_kernel(
    const float* __restrict__ x, const float* __restrict__ W_ih,
    const float* __restrict__ W_hh, const float* __restrict__ b_ih,
    const float* __restrict__ b_hh, const float* __restrict__ W_fc,
    const float* __restrict__ b_fc, float* __restrict__ out, int B)
{
    const int tid = blockIdx.x * blockDim.x + threadIdx.x;
    const int b = tid >> 4;               // batch element
    if (b >= B) return;
    const int l = threadIdx.x & 15;       // position in 16-lane group (== DPP row)
    const int j = l & 7;                  // hidden unit
    const int p = l >> 3;                 // gate-pair half

    const int rA = p ? (16 + j) : j;        // g : i
    const int rB = p ? (24 + j) : (8 + j);  // o : f

    v2f wih[4], whh[8], bias;
    #pragma unroll
    for (int k = 0; k < 4; ++k)
        wih[k] = v2f{W_ih[rA * 4 + k], W_ih[rB * 4 + k]};
    #pragma unroll
    for (int r = 0; r < 8; ++r) {
        const int m = (j - r + 8) & 7;    // unit arriving at rotation r
        whh[r] = v2f{W_hh[rA * 8 + m], W_hh[rB * 8 + m]};
    }
    bias = v2f{b_ih[rA] + b_hh[rA], b_ih[rB] + b_hh[rB]};

    // actA = sA * sigmoid(preA * a.x) + oA :  p0 -> sigmoid(i), p1 -> tanh(g)
    const float preA = p ? 2.0f : 1.0f;
    const float sA   = p ? 2.0f : 1.0f;
    const float oA   = p ? -1.0f : 0.0f;
    const bool  isP1 = (p != 0);

    const float4* xb = (const float4*)(x + (size_t)b * (T_STEPS * 4));

    // Modulo-scheduled rotating prefetch: buf[k] consumed at step base+k,
    // refilled immediately for step base+k+PF_D.
    float4 buf[PF_D];
    #pragma unroll
    for (int d = 0; d < PF_D; ++d) buf[d] = xb[d];

    float c = 0.0f, h = 0.0f;

    for (int base = 0; base < T_STEPS; base += PF_D) {
        #pragma unroll
        for (int k = 0; k < PF_D; ++k) {
            const float4 xt = buf[k];
            // refill this slot PF_D steps ahead (wraps harmlessly on last block)
            buf[k] = xb[(base + PF_D + k) & (T_STEPS - 1)];

            v2f a0 = bias, a1;
            a0.x = fmaf(xt.x, wih[0].x, a0.x); a0.y = fmaf(xt.x, wih[0].y, a0.y);
            a1 = xt.y * wih[1];
            a0 += xt.z * wih[2];
            a1 += xt.w * wih[3];
            a0 += h * whh[0];
            a1 += rotf<1>(h) * whh[1];
            a0 += rotf<2>(h) * whh[2];
            a1 += rotf<3>(h) * whh[3];
            a0 += rotf<4>(h) * whh[4];
            a1 += rotf<5>(h) * whh[5];
            a0 += rotf<6>(h) * whh[6];
            a1 += rotf<7>(h) * whh[7];
            const v2f a = a0 + a1;

            const float u    = fsigmoid(preA * a.x);
            const float actA = fmaf(u, sA, oA);    // p0: sig(i), p1: tanh(g)
            const float actB = fsigmoid(a.y);      // p0: sig(f), p1: sig(o)

            const float ig = actA * rotf<8>(actA); // i*g, select-free both halves
            const float rBv = rotf<8>(actB);
            const float f_ = isP1 ? rBv  : actB;
            const float o_ = isP1 ? actB : rBv;

            c = fmaf(f_, c, ig);
            const float tc = fmaf(fsigmoid(2.0f * c), 2.0f, -1.0f);  // tanh(c)
            h = o_ * tc;
        }
    }

    // out[b] = h . W_fc + b_fc  (both 8-lane halves hold identical h sets)
    float pr = h * W_fc[j];
    pr += __shfl_xor(pr, 1);
    pr += __shfl_xor(pr, 2);
    pr += __shfl_xor(pr, 4);
    if (l == 0) out[b] = pr + b_fc[0];
}

extern "C" void kernel_launch(void* const* d_in, const int* in_sizes, int n_in,
                              void* d_out, int out_size, void* d_ws, size_t ws_size,
                              hipStream_t stream) {
    const float* x    = (const float*)d_in[0];
    const float* W_ih = (const float*)d_in[1];
    const float* W_hh = (const float*)d_in[2];
    const float* b_ih = (const float*)d_in[3];
    const float* b_hh = (const float*)d_in[4];
    const float* W_fc = (const float*)d_in[5];
    const float* b_fc = (const float*)d_in[6];
    float* out = (float*)d_out;

    const int B = in_sizes[0] / (T_STEPS * 4);   // 8192
    const int threads = B * 16;
    const int block = 256;
    const int grid = (threads + block - 1) / block;
    lstm_kernel<<<grid, block, 0, stream>>>(x, W_ih, W_hh, b_ih, b_hh, W_fc, b_fc, out, B);
}

// Round 5
// 200.675 us; speedup vs baseline: 1.1093x; 1.1093x over previous
//
#include <hip/hip_runtime.h>

#define T_STEPS 512
#define PF_D 8            // prefetch distance (timesteps) — ~1000 cyc of cover
#define LOG2E 1.4426950408889634f

typedef float v2f __attribute__((ext_vector_type(2)));

// DPP row rotate-right by R within the 16-lane row (~2-cycle cross-lane, no LDS)
template <int R>
__device__ __forceinline__ float rotf(float v) {
    const int i = __float_as_int(v);
    return __int_as_float(__builtin_amdgcn_update_dpp(i, i, 0x120 | R, 0xF, 0xF, false));
}

// Packed fp32 FMA with scalar broadcast: d = w * {s,s} + c.
// s sits in the LOW half of an undef-high pair; op_sel_hi:[1,0,1] makes the
// high result read src1's LOW half, so the undef high is never read and the
// register allocator coalesces s in place (zero movs).
__device__ __forceinline__ v2f pk_fma_b(v2f w, float s, v2f c) {
    v2f sv; sv.x = s;
    v2f d;
    asm("v_pk_fma_f32 %0, %1, %2, %3 op_sel_hi:[1,0,1]"
        : "=v"(d) : "v"(w), "v"(sv), "v"(c));
    return d;
}
__device__ __forceinline__ void pk_fma_acc(v2f& a, v2f w, float s) {
    v2f sv; sv.x = s;
    asm("v_pk_fma_f32 %0, %1, %2, %0 op_sel_hi:[1,0,1]"
        : "+v"(a) : "v"(w), "v"(sv));
}
__device__ __forceinline__ v2f pk_mul_b(v2f w, float s) {
    v2f sv; sv.x = s;
    v2f d;
    asm("v_pk_mul_f32 %0, %1, %2 op_sel_hi:[1,0]"
        : "=v"(d) : "v"(w), "v"(sv));
    return d;
}
__device__ __forceinline__ v2f pk_add2(v2f a, v2f b) {
    v2f d;
    asm("v_pk_add_f32 %0, %1, %2" : "=v"(d) : "v"(a), "v"(b));
    return d;
}

// 16 lanes per batch element. Lane l: j = l&7 (hidden unit), p = l>>3.
// p=0 owns gate rows {i:j, f:8+j}; p=1 owns {g:16+j, o:24+j}; pairs packed in
// float2 -> forced v_pk_fma_f32. h all-gathered via DPP row_ror with per-lane-
// permuted W_hh. tanh(x)=2*sigmoid(2x)-1 keeps activations wave-uniform; the
// 2x pre-scale is folded into the exp2 constant (kA) — one mul per sigmoid.
// x prefetch: rotating 8-slot register buffer; an asm memory clobber after
// each refill makes load remat/sinking ILLEGAL (R3/R4: compiler forwarded the
// buffer away, VGPR=40, every step stalled on raw load latency).
__global__ __launch_bounds__(256, 2) void lstm_kernel(
    const float* __restrict__ x, const float* __restrict__ W_ih,
    const float* __restrict__ W_hh, const float* __restrict__ b_ih,
    const float* __restrict__ b_hh, const float* __restrict__ W_fc,
    const float* __restrict__ b_fc, float* __restrict__ out, int B)
{
    const int tid = blockIdx.x * blockDim.x + threadIdx.x;
    const int b = tid >> 4;               // batch element
    if (b >= B) return;
    const int l = threadIdx.x & 15;       // position in 16-lane group (== DPP row)
    const int j = l & 7;                  // hidden unit
    const int p = l >> 3;                 // gate-pair half

    const int rA = p ? (16 + j) : j;        // g : i
    const int rB = p ? (24 + j) : (8 + j);  // o : f

    v2f wih[4], whh[8], bias;
    #pragma unroll
    for (int k = 0; k < 4; ++k)
        wih[k] = v2f{W_ih[rA * 4 + k], W_ih[rB * 4 + k]};
    #pragma unroll
    for (int r = 0; r < 8; ++r) {
        const int m = (j - r + 8) & 7;    // unit arriving at rotation r
        whh[r] = v2f{W_hh[rA * 8 + m], W_hh[rB * 8 + m]};
    }
    bias = v2f{b_ih[rA] + b_hh[rA], b_ih[rB] + b_hh[rB]};

    // sigmoid/tanh per-lane constants: actA = sA * sigmoid-core(kA * a.x) + oA
    const float kA = p ? (-2.0f * LOG2E) : (-LOG2E);
    const float sA = p ? 2.0f : 1.0f;
    const float oA = p ? -1.0f : 0.0f;
    const bool  isP1 = (p != 0);

    const float4* xb = (const float4*)(x + (size_t)b * (T_STEPS * 4));

    float4 buf[PF_D];
    #pragma unroll
    for (int d = 0; d < PF_D; ++d) buf[d] = xb[d];
    asm volatile("" ::: "memory");   // pin prologue loads above the loop

    float c = 0.0f, h = 0.0f;

    for (int base = 0; base < T_STEPS; base += PF_D) {
        #pragma unroll
        for (int k = 0; k < PF_D; ++k) {
            const float4 xt = buf[k];
            // refill this slot PF_D steps ahead (wraps harmlessly at the end)
            buf[k] = xb[(base + PF_D + k) & (T_STEPS - 1)];
            asm volatile("" ::: "memory");   // load may not sink past here

            const float r1 = rotf<1>(h), r2 = rotf<2>(h), r3 = rotf<3>(h),
                        r4 = rotf<4>(h), r5 = rotf<5>(h), r6 = rotf<6>(h),
                        r7 = rotf<7>(h);

            v2f a0 = pk_fma_b(wih[0], xt.x, bias);
            v2f a1 = pk_mul_b(wih[1], xt.y);
            v2f a2 = pk_mul_b(whh[0], h);
            v2f a3 = pk_mul_b(whh[1], r1);
            pk_fma_acc(a0, whh[2], r2);
            pk_fma_acc(a1, whh[3], r3);
            pk_fma_acc(a2, whh[4], r4);
            pk_fma_acc(a3, whh[5], r5);
            pk_fma_acc(a0, whh[6], r6);
            pk_fma_acc(a1, whh[7], r7);
            pk_fma_acc(a2, wih[2], xt.z);
            pk_fma_acc(a3, wih[3], xt.w);
            const v2f a = pk_add2(pk_add2(a0, a1), pk_add2(a2, a3));

            const float eA = __builtin_amdgcn_exp2f(kA * a.x);
            const float eB = __builtin_amdgcn_exp2f(-LOG2E * a.y);
            const float uA = __builtin_amdgcn_rcpf(1.0f + eA);
            const float uB = __builtin_amdgcn_rcpf(1.0f + eB);
            const float actA = fmaf(uA, sA, oA);   // p0: sig(i), p1: tanh(g)
            const float actB = uB;                 // p0: sig(f), p1: sig(o)

            const float ig  = actA * rotf<8>(actA);  // i*g on both halves
            const float rBv = rotf<8>(actB);
            const float f_ = isP1 ? rBv  : actB;
            const float o_ = isP1 ? actB : rBv;

            c = fmaf(f_, c, ig);
            const float ec = __builtin_amdgcn_exp2f(-2.0f * LOG2E * c);
            const float tc = fmaf(__builtin_amdgcn_rcpf(1.0f + ec), 2.0f, -1.0f);
            h = o_ * tc;
        }
    }

    // out[b] = h . W_fc + b_fc  (both 8-lane halves hold identical h sets)
    float pr = h * W_fc[j];
    pr += __shfl_xor(pr, 1);
    pr += __shfl_xor(pr, 2);
    pr += __shfl_xor(pr, 4);
    if (l == 0) out[b] = pr + b_fc[0];
}

extern "C" void kernel_launch(void* const* d_in, const int* in_sizes, int n_in,
                              void* d_out, int out_size, void* d_ws, size_t ws_size,
                              hipStream_t stream) {
    const float* x    = (const float*)d_in[0];
    const float* W_ih = (const float*)d_in[1];
    const float* W_hh = (const float*)d_in[2];
    const float* b_ih = (const float*)d_in[3];
    const float* b_hh = (const float*)d_in[4];
    const float* W_fc = (const float*)d_in[5];
    const float* b_fc = (const float*)d_in[6];
    float* out = (float*)d_out;

    const int B = in_sizes[0] / (T_STEPS * 4);   // 8192
    const int threads = B * 16;
    const int block = 256;
    const int grid = (threads + block - 1) / block;
    lstm_kernel<<<grid, block, 0, stream>>>(x, W_ih, W_hh, b_ih, b_hh, W_fc, b_fc, out, B);
}